// Round 2
// baseline (1430.082 us; speedup 1.0000x reference)
//
#include <hip/hip_runtime.h>

// SpectralSGCN2Layer:
//   sd = h @ gate_w[0,:D]; ss = h @ gate_w[0,D:]
//   alpha = tanh(sd[dst] + ss[src] + gb)
//   e = alpha * d[dst] * d[src] * w
//   z = segment_sum(h[src] * e[:,None], dst, N)

// ---------------- Kernel A: per-node gate scores ----------------
// One wave (64 lanes) per node row; D=128 -> float2 per lane.
__global__ void node_scores_kernel(const float* __restrict__ h,
                                   const float* __restrict__ gate_w,
                                   float* __restrict__ sd,
                                   float* __restrict__ ss,
                                   int n_nodes, int D) {
    int wave = (blockIdx.x * blockDim.x + threadIdx.x) >> 6;
    int lane = threadIdx.x & 63;
    if (wave >= n_nodes) return;

    const float2* hrow = reinterpret_cast<const float2*>(h + (size_t)wave * D);
    const float2* wd   = reinterpret_cast<const float2*>(gate_w);       // first D
    const float2* ws   = reinterpret_cast<const float2*>(gate_w + D);   // second D

    float2 hv = hrow[lane];
    float2 wdv = wd[lane];
    float2 wsv = ws[lane];
    float pd = hv.x * wdv.x + hv.y * wdv.y;
    float ps = hv.x * wsv.x + hv.y * wsv.y;

    #pragma unroll
    for (int off = 32; off > 0; off >>= 1) {
        pd += __shfl_xor(pd, off, 64);
        ps += __shfl_xor(ps, off, 64);
    }
    if (lane == 0) {
        sd[wave] = pd;
        ss[wave] = ps;
    }
}

// ---------------- Kernel B: per-edge scatter-accumulate ----------------
// One wave per edge. Coefficient computed redundantly by all lanes
// (uniform-address loads coalesce to a single request). Each lane handles
// 2 columns via float2 load of h[src] + 2 f32 atomic adds into z[dst].
__global__ void edge_scatter_kernel(const float* __restrict__ h,
                                    const float* __restrict__ d,
                                    const float* __restrict__ w,
                                    const float* __restrict__ gate_b,
                                    const int* __restrict__ src,
                                    const int* __restrict__ dst,
                                    const float* __restrict__ sd,
                                    const float* __restrict__ ss,
                                    float* __restrict__ z,
                                    int n_edges, int D) {
    int wave = (blockIdx.x * blockDim.x + threadIdx.x) >> 6;
    int lane = threadIdx.x & 63;
    if (wave >= n_edges) return;

    int s = src[wave];
    int t = dst[wave];

    float alpha = tanhf(sd[t] + ss[s] + gate_b[0]);
    float c = alpha * d[t] * d[s] * w[wave];

    const float2* hrow = reinterpret_cast<const float2*>(h + (size_t)s * D);
    float2 hv = hrow[lane];

    float* zr = z + (size_t)t * D + lane * 2;
    __hip_atomic_fetch_add(zr,     hv.x * c, __ATOMIC_RELAXED, __HIP_MEMORY_SCOPE_AGENT);
    __hip_atomic_fetch_add(zr + 1, hv.y * c, __ATOMIC_RELAXED, __HIP_MEMORY_SCOPE_AGENT);
}

extern "C" void kernel_launch(void* const* d_in, const int* in_sizes, int n_in,
                              void* d_out, int out_size, void* d_ws, size_t ws_size,
                              hipStream_t stream) {
    const float* h      = (const float*)d_in[0];
    const float* d      = (const float*)d_in[1];
    const float* w      = (const float*)d_in[2];
    const float* gate_w = (const float*)d_in[3];
    const float* gate_b = (const float*)d_in[4];
    const int*   src    = (const int*)d_in[5];
    const int*   dst    = (const int*)d_in[6];
    float*       z      = (float*)d_out;

    const int n_nodes = in_sizes[1];
    const int n_edges = in_sizes[2];
    const int D       = in_sizes[3] / 2;

    float* sd = (float*)d_ws;
    float* ss = sd + n_nodes;

    // z is poisoned 0xAA before every timed launch — zero it.
    hipMemsetAsync(d_out, 0, (size_t)out_size * sizeof(float), stream);

    // Kernel A: 4 waves per 256-thread block -> 4 nodes per block.
    {
        int waves_per_block = 4;
        int blocks = (n_nodes + waves_per_block - 1) / waves_per_block;
        node_scores_kernel<<<blocks, 256, 0, stream>>>(h, gate_w, sd, ss, n_nodes, D);
    }

    // Kernel B: 4 waves per block -> 4 edges per block.
    {
        int waves_per_block = 4;
        int blocks = (n_edges + waves_per_block - 1) / waves_per_block;
        edge_scatter_kernel<<<blocks, 256, 0, stream>>>(h, d, w, gate_b, src, dst,
                                                        sd, ss, z, n_edges, D);
    }
}

// Round 4
// 439.244 us; speedup vs baseline: 3.2558x; 3.2558x over previous
//
#include <hip/hip_runtime.h>

// SpectralSGCN2Layer:
//   sd = h @ gate_w[0,:D]; ss = h @ gate_w[0,D:]
//   alpha = tanh(sd[dst] + ss[src] + gb)
//   e = alpha * d[dst] * d[src] * w
//   z = segment_sum(h[src] * e[:,None], dst, N)
//
// Round 3: replace f32 atomic scatter (atomic-RMW bound, 1.6 GB WRITE_SIZE)
// with on-device counting sort by dst (CSR) + per-node register accumulation.

// ---------------- Kernel A: per-node gate scores ----------------
__global__ void node_scores_kernel(const float* __restrict__ h,
                                   const float* __restrict__ gate_w,
                                   float* __restrict__ sd,
                                   float* __restrict__ ss,
                                   int n_nodes, int D) {
    int wave = (blockIdx.x * blockDim.x + threadIdx.x) >> 6;
    int lane = threadIdx.x & 63;
    if (wave >= n_nodes) return;

    const float2* hrow = reinterpret_cast<const float2*>(h + (size_t)wave * D);
    const float2* wd   = reinterpret_cast<const float2*>(gate_w);
    const float2* ws   = reinterpret_cast<const float2*>(gate_w + D);

    float2 hv = hrow[lane];
    float2 wdv = wd[lane];
    float2 wsv = ws[lane];
    float pd = hv.x * wdv.x + hv.y * wdv.y;
    float ps = hv.x * wsv.x + hv.y * wsv.y;

    #pragma unroll
    for (int off = 32; off > 0; off >>= 1) {
        pd += __shfl_xor(pd, off, 64);
        ps += __shfl_xor(ps, off, 64);
    }
    if (lane == 0) {
        sd[wave] = pd;
        ss[wave] = ps;
    }
}

// ---------------- Histogram of dst ----------------
__global__ void hist_kernel(const int* __restrict__ dst,
                            int* __restrict__ deg, int n_edges) {
    int e = blockIdx.x * blockDim.x + threadIdx.x;
    if (e >= n_edges) return;
    atomicAdd(&deg[dst[e]], 1);
}

// ---------------- Exclusive scan (3 stages, 256-wide blocks) ----------------
__global__ void scan1_kernel(const int* __restrict__ deg,
                             int* __restrict__ offs,
                             int* __restrict__ bsums, int n) {
    __shared__ int tmp[256];
    int i = blockIdx.x * 256 + threadIdx.x;
    int v = (i < n) ? deg[i] : 0;
    tmp[threadIdx.x] = v;
    __syncthreads();
    #pragma unroll
    for (int off = 1; off < 256; off <<= 1) {
        int t = (threadIdx.x >= off) ? tmp[threadIdx.x - off] : 0;
        __syncthreads();
        tmp[threadIdx.x] += t;
        __syncthreads();
    }
    if (i < n) offs[i] = tmp[threadIdx.x] - v;  // exclusive
    if (threadIdx.x == 255) bsums[blockIdx.x] = tmp[255];
}

__global__ void scan2_kernel(int* __restrict__ bsums, int nb) {
    __shared__ int tmp[256];
    int carry = 0;
    for (int base = 0; base < nb; base += 256) {
        int i = base + threadIdx.x;
        int v = (i < nb) ? bsums[i] : 0;
        tmp[threadIdx.x] = v;
        __syncthreads();
        #pragma unroll
        for (int off = 1; off < 256; off <<= 1) {
            int t = (threadIdx.x >= off) ? tmp[threadIdx.x - off] : 0;
            __syncthreads();
            tmp[threadIdx.x] += t;
            __syncthreads();
        }
        if (i < nb) bsums[i] = tmp[threadIdx.x] - v + carry;
        int total = tmp[255];
        __syncthreads();
        carry += total;
    }
}

__global__ void scan3_kernel(int* __restrict__ offs,
                             const int* __restrict__ bsums,
                             int* __restrict__ cursor, int n) {
    int i = blockIdx.x * 256 + threadIdx.x;
    if (i < n) {
        int o = offs[i] + bsums[blockIdx.x];
        offs[i] = o;
        cursor[i] = o;
    }
}

// ---------------- Scatter edges into CSR order + coefficient ----------------
__global__ void scatter_kernel(const float* __restrict__ d,
                               const float* __restrict__ w,
                               const float* __restrict__ gate_b,
                               const int* __restrict__ src,
                               const int* __restrict__ dst,
                               const float* __restrict__ sd,
                               const float* __restrict__ ss,
                               int* __restrict__ cursor,
                               int* __restrict__ src_sorted,
                               float* __restrict__ c_sorted,
                               int n_edges) {
    int e = blockIdx.x * blockDim.x + threadIdx.x;
    if (e >= n_edges) return;
    int s = src[e];
    int t = dst[e];
    float alpha = tanhf(sd[t] + ss[s] + gate_b[0]);
    float c = alpha * d[t] * d[s] * w[e];
    int pos = atomicAdd(&cursor[t], 1);
    src_sorted[pos] = s;
    c_sorted[pos]  = c;
}

// ---------------- Per-node gather-accumulate (no atomics) ----------------
// One wave per node; each lane owns 2 columns (float2). 2-edge unroll for ILP.
__global__ void gather_kernel(const float* __restrict__ h,
                              const int* __restrict__ offs,
                              const int* __restrict__ deg,
                              const int* __restrict__ src_sorted,
                              const float* __restrict__ c_sorted,
                              float* __restrict__ z,
                              int n_nodes, int D) {
    int wave = (blockIdx.x * blockDim.x + threadIdx.x) >> 6;
    int lane = threadIdx.x & 63;
    if (wave >= n_nodes) return;

    int beg = offs[wave];
    int cnt = deg[wave];

    float2 acc = make_float2(0.f, 0.f);
    int k = 0;
    for (; k + 1 < cnt; k += 2) {
        int   s0 = src_sorted[beg + k];
        int   s1 = src_sorted[beg + k + 1];
        float c0 = c_sorted[beg + k];
        float c1 = c_sorted[beg + k + 1];
        float2 h0 = reinterpret_cast<const float2*>(h + (size_t)s0 * D)[lane];
        float2 h1 = reinterpret_cast<const float2*>(h + (size_t)s1 * D)[lane];
        acc.x += c0 * h0.x + c1 * h1.x;
        acc.y += c0 * h0.y + c1 * h1.y;
    }
    if (k < cnt) {
        int   s0 = src_sorted[beg + k];
        float c0 = c_sorted[beg + k];
        float2 h0 = reinterpret_cast<const float2*>(h + (size_t)s0 * D)[lane];
        acc.x += c0 * h0.x;
        acc.y += c0 * h0.y;
    }
    reinterpret_cast<float2*>(z + (size_t)wave * D)[lane] = acc;
}

// ---------------- Fallback: per-edge atomic scatter (round-2 kernel) ----------------
__global__ void edge_scatter_kernel(const float* __restrict__ h,
                                    const float* __restrict__ d,
                                    const float* __restrict__ w,
                                    const float* __restrict__ gate_b,
                                    const int* __restrict__ src,
                                    const int* __restrict__ dst,
                                    const float* __restrict__ sd,
                                    const float* __restrict__ ss,
                                    float* __restrict__ z,
                                    int n_edges, int D) {
    int wave = (blockIdx.x * blockDim.x + threadIdx.x) >> 6;
    int lane = threadIdx.x & 63;
    if (wave >= n_edges) return;
    int s = src[wave];
    int t = dst[wave];
    float alpha = tanhf(sd[t] + ss[s] + gate_b[0]);
    float c = alpha * d[t] * d[s] * w[wave];
    const float2* hrow = reinterpret_cast<const float2*>(h + (size_t)s * D);
    float2 hv = hrow[lane];
    float* zr = z + (size_t)t * D + lane * 2;
    __hip_atomic_fetch_add(zr,     hv.x * c, __ATOMIC_RELAXED, __HIP_MEMORY_SCOPE_AGENT);
    __hip_atomic_fetch_add(zr + 1, hv.y * c, __ATOMIC_RELAXED, __HIP_MEMORY_SCOPE_AGENT);
}

extern "C" void kernel_launch(void* const* d_in, const int* in_sizes, int n_in,
                              void* d_out, int out_size, void* d_ws, size_t ws_size,
                              hipStream_t stream) {
    const float* h      = (const float*)d_in[0];
    const float* d      = (const float*)d_in[1];
    const float* w      = (const float*)d_in[2];
    const float* gate_w = (const float*)d_in[3];
    const float* gate_b = (const float*)d_in[4];
    const int*   src    = (const int*)d_in[5];
    const int*   dst    = (const int*)d_in[6];
    float*       z      = (float*)d_out;

    const int n_nodes = in_sizes[1];
    const int n_edges = in_sizes[2];
    const int D       = in_sizes[3] / 2;

    const int NB = (n_nodes + 255) / 256;  // scan blocks

    // Workspace layout (all 4-byte elems):
    // sd[N] ss[N] deg[N] offs[N] cursor[N] bsums[NB] src_sorted[E] c_sorted[E]
    size_t need = ((size_t)n_nodes * 5 + NB + (size_t)n_edges * 2) * 4;

    float* sd = (float*)d_ws;
    float* ss = sd + n_nodes;

    // Kernel A: gate scores (needed by both paths).
    {
        int blocks = (n_nodes + 3) / 4;  // 4 waves/block
        node_scores_kernel<<<blocks, 256, 0, stream>>>(h, gate_w, sd, ss, n_nodes, D);
    }

    if (need <= ws_size) {
        int*   deg        = (int*)(ss + n_nodes);
        int*   offs       = deg + n_nodes;
        int*   cursor     = offs + n_nodes;
        int*   bsums      = cursor + n_nodes;
        int*   src_sorted = bsums + NB;
        float* c_sorted   = (float*)(src_sorted + n_edges);

        hipMemsetAsync(deg, 0, (size_t)n_nodes * 4, stream);

        int eblocks = (n_edges + 255) / 256;
        hist_kernel<<<eblocks, 256, 0, stream>>>(dst, deg, n_edges);
        scan1_kernel<<<NB, 256, 0, stream>>>(deg, offs, bsums, n_nodes);
        scan2_kernel<<<1, 256, 0, stream>>>(bsums, NB);
        scan3_kernel<<<NB, 256, 0, stream>>>(offs, bsums, cursor, n_nodes);
        scatter_kernel<<<eblocks, 256, 0, stream>>>(d, w, gate_b, src, dst, sd, ss,
                                                    cursor, src_sorted, c_sorted, n_edges);
        int gblocks = (n_nodes + 3) / 4;  // 4 waves/block
        gather_kernel<<<gblocks, 256, 0, stream>>>(h, offs, deg, src_sorted, c_sorted,
                                                   z, n_nodes, D);
    } else {
        // Fallback: atomic scatter path.
        hipMemsetAsync(d_out, 0, (size_t)out_size * sizeof(float), stream);
        int blocks = (n_edges + 3) / 4;
        edge_scatter_kernel<<<blocks, 256, 0, stream>>>(h, d, w, gate_b, src, dst,
                                                        sd, ss, z, n_edges, D);
    }
}

// Round 5
// 401.138 us; speedup vs baseline: 3.5651x; 1.0950x over previous
//
#include <hip/hip_runtime.h>

// SpectralSGCN2Layer:
//   sd = h @ gate_w[0,:D]; ss = h @ gate_w[0,D:]
//   alpha = tanh(sd[dst] + ss[src] + gb)
//   e = alpha * d[dst] * d[src] * w
//   z = segment_sum(h[src] * e[:,None], dst, N)
//
// Round 5: pack scatter payload into one int2 (src, c) -> 1 random line/edge
// instead of 2; 4-edge unroll in gather for L3-latency hiding.

// ---------------- Kernel A: per-node gate scores ----------------
__global__ void node_scores_kernel(const float* __restrict__ h,
                                   const float* __restrict__ gate_w,
                                   float* __restrict__ sd,
                                   float* __restrict__ ss,
                                   int n_nodes, int D) {
    int wave = (blockIdx.x * blockDim.x + threadIdx.x) >> 6;
    int lane = threadIdx.x & 63;
    if (wave >= n_nodes) return;

    const float2* hrow = reinterpret_cast<const float2*>(h + (size_t)wave * D);
    const float2* wd   = reinterpret_cast<const float2*>(gate_w);
    const float2* ws   = reinterpret_cast<const float2*>(gate_w + D);

    float2 hv = hrow[lane];
    float2 wdv = wd[lane];
    float2 wsv = ws[lane];
    float pd = hv.x * wdv.x + hv.y * wdv.y;
    float ps = hv.x * wsv.x + hv.y * wsv.y;

    #pragma unroll
    for (int off = 32; off > 0; off >>= 1) {
        pd += __shfl_xor(pd, off, 64);
        ps += __shfl_xor(ps, off, 64);
    }
    if (lane == 0) {
        sd[wave] = pd;
        ss[wave] = ps;
    }
}

// ---------------- Histogram of dst ----------------
__global__ void hist_kernel(const int* __restrict__ dst,
                            int* __restrict__ deg, int n_edges) {
    int e = blockIdx.x * blockDim.x + threadIdx.x;
    if (e >= n_edges) return;
    atomicAdd(&deg[dst[e]], 1);
}

// ---------------- Exclusive scan (3 stages, 256-wide blocks) ----------------
__global__ void scan1_kernel(const int* __restrict__ deg,
                             int* __restrict__ offs,
                             int* __restrict__ bsums, int n) {
    __shared__ int tmp[256];
    int i = blockIdx.x * 256 + threadIdx.x;
    int v = (i < n) ? deg[i] : 0;
    tmp[threadIdx.x] = v;
    __syncthreads();
    #pragma unroll
    for (int off = 1; off < 256; off <<= 1) {
        int t = (threadIdx.x >= off) ? tmp[threadIdx.x - off] : 0;
        __syncthreads();
        tmp[threadIdx.x] += t;
        __syncthreads();
    }
    if (i < n) offs[i] = tmp[threadIdx.x] - v;  // exclusive
    if (threadIdx.x == 255) bsums[blockIdx.x] = tmp[255];
}

__global__ void scan2_kernel(int* __restrict__ bsums, int nb) {
    __shared__ int tmp[256];
    int carry = 0;
    for (int base = 0; base < nb; base += 256) {
        int i = base + threadIdx.x;
        int v = (i < nb) ? bsums[i] : 0;
        tmp[threadIdx.x] = v;
        __syncthreads();
        #pragma unroll
        for (int off = 1; off < 256; off <<= 1) {
            int t = (threadIdx.x >= off) ? tmp[threadIdx.x - off] : 0;
            __syncthreads();
            tmp[threadIdx.x] += t;
            __syncthreads();
        }
        if (i < nb) bsums[i] = tmp[threadIdx.x] - v + carry;
        int total = tmp[255];
        __syncthreads();
        carry += total;
    }
}

__global__ void scan3_kernel(int* __restrict__ offs,
                             const int* __restrict__ bsums,
                             int* __restrict__ cursor, int n) {
    int i = blockIdx.x * 256 + threadIdx.x;
    if (i < n) {
        int o = offs[i] + bsums[blockIdx.x];
        offs[i] = o;
        cursor[i] = o;
    }
}

// ---------------- Scatter edges into CSR order (packed int2) ----------------
__global__ void scatter_kernel(const float* __restrict__ d,
                               const float* __restrict__ w,
                               const float* __restrict__ gate_b,
                               const int* __restrict__ src,
                               const int* __restrict__ dst,
                               const float* __restrict__ sd,
                               const float* __restrict__ ss,
                               int* __restrict__ cursor,
                               int2* __restrict__ ec_sorted,
                               int n_edges) {
    int e = blockIdx.x * blockDim.x + threadIdx.x;
    if (e >= n_edges) return;
    int s = src[e];
    int t = dst[e];
    float alpha = tanhf(sd[t] + ss[s] + gate_b[0]);
    float c = alpha * d[t] * d[s] * w[e];
    int pos = atomicAdd(&cursor[t], 1);
    ec_sorted[pos] = make_int2(s, __float_as_int(c));
}

// ---------------- Per-node gather-accumulate (no atomics) ----------------
// One wave per node; each lane owns 2 columns (float2). 4-edge unroll for MLP.
__global__ void gather_kernel(const float* __restrict__ h,
                              const int* __restrict__ offs,
                              const int* __restrict__ deg,
                              const int2* __restrict__ ec_sorted,
                              float* __restrict__ z,
                              int n_nodes, int D) {
    int wave = (blockIdx.x * blockDim.x + threadIdx.x) >> 6;
    int lane = threadIdx.x & 63;
    if (wave >= n_nodes) return;

    int beg = offs[wave];
    int cnt = deg[wave];

    float2 acc = make_float2(0.f, 0.f);
    int k = 0;
    for (; k + 3 < cnt; k += 4) {
        int2 e0 = ec_sorted[beg + k];
        int2 e1 = ec_sorted[beg + k + 1];
        int2 e2 = ec_sorted[beg + k + 2];
        int2 e3 = ec_sorted[beg + k + 3];
        float2 h0 = reinterpret_cast<const float2*>(h + (size_t)e0.x * D)[lane];
        float2 h1 = reinterpret_cast<const float2*>(h + (size_t)e1.x * D)[lane];
        float2 h2 = reinterpret_cast<const float2*>(h + (size_t)e2.x * D)[lane];
        float2 h3 = reinterpret_cast<const float2*>(h + (size_t)e3.x * D)[lane];
        float c0 = __int_as_float(e0.y);
        float c1 = __int_as_float(e1.y);
        float c2 = __int_as_float(e2.y);
        float c3 = __int_as_float(e3.y);
        acc.x += c0 * h0.x + c1 * h1.x + c2 * h2.x + c3 * h3.x;
        acc.y += c0 * h0.y + c1 * h1.y + c2 * h2.y + c3 * h3.y;
    }
    for (; k < cnt; ++k) {
        int2 e0 = ec_sorted[beg + k];
        float2 h0 = reinterpret_cast<const float2*>(h + (size_t)e0.x * D)[lane];
        float c0 = __int_as_float(e0.y);
        acc.x += c0 * h0.x;
        acc.y += c0 * h0.y;
    }
    reinterpret_cast<float2*>(z + (size_t)wave * D)[lane] = acc;
}

// ---------------- Fallback: per-edge atomic scatter (round-2 kernel) ----------------
__global__ void edge_scatter_kernel(const float* __restrict__ h,
                                    const float* __restrict__ d,
                                    const float* __restrict__ w,
                                    const float* __restrict__ gate_b,
                                    const int* __restrict__ src,
                                    const int* __restrict__ dst,
                                    const float* __restrict__ sd,
                                    const float* __restrict__ ss,
                                    float* __restrict__ z,
                                    int n_edges, int D) {
    int wave = (blockIdx.x * blockDim.x + threadIdx.x) >> 6;
    int lane = threadIdx.x & 63;
    if (wave >= n_edges) return;
    int s = src[wave];
    int t = dst[wave];
    float alpha = tanhf(sd[t] + ss[s] + gate_b[0]);
    float c = alpha * d[t] * d[s] * w[wave];
    const float2* hrow = reinterpret_cast<const float2*>(h + (size_t)s * D);
    float2 hv = hrow[lane];
    float* zr = z + (size_t)t * D + lane * 2;
    __hip_atomic_fetch_add(zr,     hv.x * c, __ATOMIC_RELAXED, __HIP_MEMORY_SCOPE_AGENT);
    __hip_atomic_fetch_add(zr + 1, hv.y * c, __ATOMIC_RELAXED, __HIP_MEMORY_SCOPE_AGENT);
}

extern "C" void kernel_launch(void* const* d_in, const int* in_sizes, int n_in,
                              void* d_out, int out_size, void* d_ws, size_t ws_size,
                              hipStream_t stream) {
    const float* h      = (const float*)d_in[0];
    const float* d      = (const float*)d_in[1];
    const float* w      = (const float*)d_in[2];
    const float* gate_w = (const float*)d_in[3];
    const float* gate_b = (const float*)d_in[4];
    const int*   src    = (const int*)d_in[5];
    const int*   dst    = (const int*)d_in[6];
    float*       z      = (float*)d_out;

    const int n_nodes = in_sizes[1];
    const int n_edges = in_sizes[2];
    const int D       = in_sizes[3] / 2;

    const int NB = (n_nodes + 255) / 256;  // scan blocks

    // Workspace layout (ints unless noted):
    // sd[N] ss[N] deg[N] offs[N] cursor[N] bsums[NB] [pad to 8B] ec_sorted[E] (int2)
    size_t head_elems = (size_t)n_nodes * 5 + NB;
    head_elems = (head_elems + 1) & ~(size_t)1;  // 8B-align ec_sorted
    size_t need = head_elems * 4 + (size_t)n_edges * 8;

    float* sd = (float*)d_ws;
    float* ss = sd + n_nodes;

    // Kernel A: gate scores (needed by both paths).
    {
        int blocks = (n_nodes + 3) / 4;  // 4 waves/block
        node_scores_kernel<<<blocks, 256, 0, stream>>>(h, gate_w, sd, ss, n_nodes, D);
    }

    if (need <= ws_size) {
        int*  deg       = (int*)(ss + n_nodes);
        int*  offs      = deg + n_nodes;
        int*  cursor    = offs + n_nodes;
        int*  bsums     = cursor + n_nodes;
        int2* ec_sorted = (int2*)((int*)d_ws + head_elems);

        hipMemsetAsync(deg, 0, (size_t)n_nodes * 4, stream);

        int eblocks = (n_edges + 255) / 256;
        hist_kernel<<<eblocks, 256, 0, stream>>>(dst, deg, n_edges);
        scan1_kernel<<<NB, 256, 0, stream>>>(deg, offs, bsums, n_nodes);
        scan2_kernel<<<1, 256, 0, stream>>>(bsums, NB);
        scan3_kernel<<<NB, 256, 0, stream>>>(offs, bsums, cursor, n_nodes);
        scatter_kernel<<<eblocks, 256, 0, stream>>>(d, w, gate_b, src, dst, sd, ss,
                                                    cursor, ec_sorted, n_edges);
        int gblocks = (n_nodes + 3) / 4;  // 4 waves/block
        gather_kernel<<<gblocks, 256, 0, stream>>>(h, offs, deg, ec_sorted,
                                                   z, n_nodes, D);
    } else {
        // Fallback: atomic scatter path.
        hipMemsetAsync(d_out, 0, (size_t)out_size * sizeof(float), stream);
        int blocks = (n_edges + 3) / 4;
        edge_scatter_kernel<<<blocks, 256, 0, stream>>>(h, d, w, gate_b, src, dst,
                                                        sd, ss, z, n_edges, D);
    }
}

// Round 6
// 391.044 us; speedup vs baseline: 3.6571x; 1.0258x over previous
//
#include <hip/hip_runtime.h>

// SpectralSGCN2Layer:
//   sd = h @ gate_w[0,:D]; ss = h @ gate_w[0,D:]
//   alpha = tanh(sd[dst] + ss[src] + gb)
//   e = alpha * d[dst] * d[src] * w
//   z = segment_sum(h[src] * e[:,None], dst, N)
//
// Round 6: gather h in bf16 (halves the dominant random-gather traffic:
// 512 B/edge -> 256 B/edge). h converted once per call (streamed, ~12 us).
// Accumulate f32. Error budget: threshold 0.1425, previously 0.0156.

// ---------------- Kernel A: per-node gate scores ----------------
__global__ void node_scores_kernel(const float* __restrict__ h,
                                   const float* __restrict__ gate_w,
                                   float* __restrict__ sd,
                                   float* __restrict__ ss,
                                   int n_nodes, int D) {
    int wave = (blockIdx.x * blockDim.x + threadIdx.x) >> 6;
    int lane = threadIdx.x & 63;
    if (wave >= n_nodes) return;

    const float2* hrow = reinterpret_cast<const float2*>(h + (size_t)wave * D);
    const float2* wd   = reinterpret_cast<const float2*>(gate_w);
    const float2* ws   = reinterpret_cast<const float2*>(gate_w + D);

    float2 hv = hrow[lane];
    float2 wdv = wd[lane];
    float2 wsv = ws[lane];
    float pd = hv.x * wdv.x + hv.y * wdv.y;
    float ps = hv.x * wsv.x + hv.y * wsv.y;

    #pragma unroll
    for (int off = 32; off > 0; off >>= 1) {
        pd += __shfl_xor(pd, off, 64);
        ps += __shfl_xor(ps, off, 64);
    }
    if (lane == 0) {
        sd[wave] = pd;
        ss[wave] = ps;
    }
}

// ---------------- h (f32) -> hb (bf16 packed pairs, RNE) ----------------
__device__ __forceinline__ unsigned bf16_rne(float f) {
    unsigned u = __float_as_uint(f);
    return (u + 0x7fffu + ((u >> 16) & 1u)) >> 16;
}

__global__ void h2bf16_kernel(const float2* __restrict__ h2,
                              unsigned* __restrict__ hb, size_t n2) {
    size_t i = (size_t)blockIdx.x * blockDim.x + threadIdx.x;
    if (i >= n2) return;
    float2 v = h2[i];
    hb[i] = bf16_rne(v.x) | (bf16_rne(v.y) << 16);
}

// ---------------- Histogram of dst ----------------
__global__ void hist_kernel(const int* __restrict__ dst,
                            int* __restrict__ deg, int n_edges) {
    int e = blockIdx.x * blockDim.x + threadIdx.x;
    if (e >= n_edges) return;
    atomicAdd(&deg[dst[e]], 1);
}

// ---------------- Exclusive scan (3 stages, 256-wide blocks) ----------------
__global__ void scan1_kernel(const int* __restrict__ deg,
                             int* __restrict__ offs,
                             int* __restrict__ bsums, int n) {
    __shared__ int tmp[256];
    int i = blockIdx.x * 256 + threadIdx.x;
    int v = (i < n) ? deg[i] : 0;
    tmp[threadIdx.x] = v;
    __syncthreads();
    #pragma unroll
    for (int off = 1; off < 256; off <<= 1) {
        int t = (threadIdx.x >= off) ? tmp[threadIdx.x - off] : 0;
        __syncthreads();
        tmp[threadIdx.x] += t;
        __syncthreads();
    }
    if (i < n) offs[i] = tmp[threadIdx.x] - v;  // exclusive
    if (threadIdx.x == 255) bsums[blockIdx.x] = tmp[255];
}

__global__ void scan2_kernel(int* __restrict__ bsums, int nb) {
    __shared__ int tmp[256];
    int carry = 0;
    for (int base = 0; base < nb; base += 256) {
        int i = base + threadIdx.x;
        int v = (i < nb) ? bsums[i] : 0;
        tmp[threadIdx.x] = v;
        __syncthreads();
        #pragma unroll
        for (int off = 1; off < 256; off <<= 1) {
            int t = (threadIdx.x >= off) ? tmp[threadIdx.x - off] : 0;
            __syncthreads();
            tmp[threadIdx.x] += t;
            __syncthreads();
        }
        if (i < nb) bsums[i] = tmp[threadIdx.x] - v + carry;
        int total = tmp[255];
        __syncthreads();
        carry += total;
    }
}

__global__ void scan3_kernel(int* __restrict__ offs,
                             const int* __restrict__ bsums,
                             int* __restrict__ cursor, int n) {
    int i = blockIdx.x * 256 + threadIdx.x;
    if (i < n) {
        int o = offs[i] + bsums[blockIdx.x];
        offs[i] = o;
        cursor[i] = o;
    }
}

// ---------------- Scatter edges into CSR order (packed int2) ----------------
__global__ void scatter_kernel(const float* __restrict__ d,
                               const float* __restrict__ w,
                               const float* __restrict__ gate_b,
                               const int* __restrict__ src,
                               const int* __restrict__ dst,
                               const float* __restrict__ sd,
                               const float* __restrict__ ss,
                               int* __restrict__ cursor,
                               int2* __restrict__ ec_sorted,
                               int n_edges) {
    int e = blockIdx.x * blockDim.x + threadIdx.x;
    if (e >= n_edges) return;
    int s = src[e];
    int t = dst[e];
    float alpha = tanhf(sd[t] + ss[s] + gate_b[0]);
    float c = alpha * d[t] * d[s] * w[e];
    int pos = atomicAdd(&cursor[t], 1);
    ec_sorted[pos] = make_int2(s, __float_as_int(c));
}

// ---------------- Per-node gather-accumulate, bf16 h ----------------
// One wave per node; each lane owns 2 columns (one packed bf16 pair, 4 B).
__global__ void gather_bf16_kernel(const unsigned* __restrict__ hb,
                                   const int* __restrict__ offs,
                                   const int* __restrict__ deg,
                                   const int2* __restrict__ ec_sorted,
                                   float* __restrict__ z,
                                   int n_nodes, int D) {
    int wave = (blockIdx.x * blockDim.x + threadIdx.x) >> 6;
    int lane = threadIdx.x & 63;
    if (wave >= n_nodes) return;

    int beg = offs[wave];
    int cnt = deg[wave];
    int D2 = D >> 1;

    float accx = 0.f, accy = 0.f;
    int k = 0;
    for (; k + 3 < cnt; k += 4) {
        int2 e0 = ec_sorted[beg + k];
        int2 e1 = ec_sorted[beg + k + 1];
        int2 e2 = ec_sorted[beg + k + 2];
        int2 e3 = ec_sorted[beg + k + 3];
        unsigned v0 = hb[(size_t)e0.x * D2 + lane];
        unsigned v1 = hb[(size_t)e1.x * D2 + lane];
        unsigned v2 = hb[(size_t)e2.x * D2 + lane];
        unsigned v3 = hb[(size_t)e3.x * D2 + lane];
        float c0 = __int_as_float(e0.y);
        float c1 = __int_as_float(e1.y);
        float c2 = __int_as_float(e2.y);
        float c3 = __int_as_float(e3.y);
        accx += c0 * __uint_as_float(v0 << 16) + c1 * __uint_as_float(v1 << 16)
              + c2 * __uint_as_float(v2 << 16) + c3 * __uint_as_float(v3 << 16);
        accy += c0 * __uint_as_float(v0 & 0xffff0000u) + c1 * __uint_as_float(v1 & 0xffff0000u)
              + c2 * __uint_as_float(v2 & 0xffff0000u) + c3 * __uint_as_float(v3 & 0xffff0000u);
    }
    for (; k < cnt; ++k) {
        int2 e0 = ec_sorted[beg + k];
        unsigned v0 = hb[(size_t)e0.x * D2 + lane];
        float c0 = __int_as_float(e0.y);
        accx += c0 * __uint_as_float(v0 << 16);
        accy += c0 * __uint_as_float(v0 & 0xffff0000u);
    }
    reinterpret_cast<float2*>(z + (size_t)wave * D)[lane] = make_float2(accx, accy);
}

// ---------------- f32 gather (fallback if bf16 copy doesn't fit ws) ------
__global__ void gather_f32_kernel(const float* __restrict__ h,
                                  const int* __restrict__ offs,
                                  const int* __restrict__ deg,
                                  const int2* __restrict__ ec_sorted,
                                  float* __restrict__ z,
                                  int n_nodes, int D) {
    int wave = (blockIdx.x * blockDim.x + threadIdx.x) >> 6;
    int lane = threadIdx.x & 63;
    if (wave >= n_nodes) return;

    int beg = offs[wave];
    int cnt = deg[wave];

    float2 acc = make_float2(0.f, 0.f);
    int k = 0;
    for (; k + 3 < cnt; k += 4) {
        int2 e0 = ec_sorted[beg + k];
        int2 e1 = ec_sorted[beg + k + 1];
        int2 e2 = ec_sorted[beg + k + 2];
        int2 e3 = ec_sorted[beg + k + 3];
        float2 h0 = reinterpret_cast<const float2*>(h + (size_t)e0.x * D)[lane];
        float2 h1 = reinterpret_cast<const float2*>(h + (size_t)e1.x * D)[lane];
        float2 h2 = reinterpret_cast<const float2*>(h + (size_t)e2.x * D)[lane];
        float2 h3 = reinterpret_cast<const float2*>(h + (size_t)e3.x * D)[lane];
        float c0 = __int_as_float(e0.y);
        float c1 = __int_as_float(e1.y);
        float c2 = __int_as_float(e2.y);
        float c3 = __int_as_float(e3.y);
        acc.x += c0 * h0.x + c1 * h1.x + c2 * h2.x + c3 * h3.x;
        acc.y += c0 * h0.y + c1 * h1.y + c2 * h2.y + c3 * h3.y;
    }
    for (; k < cnt; ++k) {
        int2 e0 = ec_sorted[beg + k];
        float2 h0 = reinterpret_cast<const float2*>(h + (size_t)e0.x * D)[lane];
        float c0 = __int_as_float(e0.y);
        acc.x += c0 * h0.x;
        acc.y += c0 * h0.y;
    }
    reinterpret_cast<float2*>(z + (size_t)wave * D)[lane] = acc;
}

// ---------------- Fallback: per-edge atomic scatter ----------------
__global__ void edge_scatter_kernel(const float* __restrict__ h,
                                    const float* __restrict__ d,
                                    const float* __restrict__ w,
                                    const float* __restrict__ gate_b,
                                    const int* __restrict__ src,
                                    const int* __restrict__ dst,
                                    const float* __restrict__ sd,
                                    const float* __restrict__ ss,
                                    float* __restrict__ z,
                                    int n_edges, int D) {
    int wave = (blockIdx.x * blockDim.x + threadIdx.x) >> 6;
    int lane = threadIdx.x & 63;
    if (wave >= n_edges) return;
    int s = src[wave];
    int t = dst[wave];
    float alpha = tanhf(sd[t] + ss[s] + gate_b[0]);
    float c = alpha * d[t] * d[s] * w[wave];
    const float2* hrow = reinterpret_cast<const float2*>(h + (size_t)s * D);
    float2 hv = hrow[lane];
    float* zr = z + (size_t)t * D + lane * 2;
    __hip_atomic_fetch_add(zr,     hv.x * c, __ATOMIC_RELAXED, __HIP_MEMORY_SCOPE_AGENT);
    __hip_atomic_fetch_add(zr + 1, hv.y * c, __ATOMIC_RELAXED, __HIP_MEMORY_SCOPE_AGENT);
}

extern "C" void kernel_launch(void* const* d_in, const int* in_sizes, int n_in,
                              void* d_out, int out_size, void* d_ws, size_t ws_size,
                              hipStream_t stream) {
    const float* h      = (const float*)d_in[0];
    const float* d      = (const float*)d_in[1];
    const float* w      = (const float*)d_in[2];
    const float* gate_w = (const float*)d_in[3];
    const float* gate_b = (const float*)d_in[4];
    const int*   src    = (const int*)d_in[5];
    const int*   dst    = (const int*)d_in[6];
    float*       z      = (float*)d_out;

    const int n_nodes = in_sizes[1];
    const int n_edges = in_sizes[2];
    const int D       = in_sizes[3] / 2;

    const int NB = (n_nodes + 255) / 256;  // scan blocks

    // Workspace layout (4B elems unless noted):
    // sd[N] ss[N] deg[N] offs[N] cursor[N] bsums[NB] [pad8] ec_sorted[E](int2) hb[N*D/2](u32)
    size_t head_elems = (size_t)n_nodes * 5 + NB;
    head_elems = (head_elems + 1) & ~(size_t)1;  // 8B-align ec_sorted
    size_t n_hb       = (size_t)n_nodes * (D / 2);
    size_t need_csr   = head_elems * 4 + (size_t)n_edges * 8;
    size_t need_bf16  = need_csr + n_hb * 4;

    float* sd = (float*)d_ws;
    float* ss = sd + n_nodes;

    // Kernel A: gate scores (needed by all paths).
    {
        int blocks = (n_nodes + 3) / 4;  // 4 waves/block
        node_scores_kernel<<<blocks, 256, 0, stream>>>(h, gate_w, sd, ss, n_nodes, D);
    }

    if (need_csr <= ws_size) {
        int*  deg       = (int*)(ss + n_nodes);
        int*  offs      = deg + n_nodes;
        int*  cursor    = offs + n_nodes;
        int*  bsums     = cursor + n_nodes;
        int2* ec_sorted = (int2*)((int*)d_ws + head_elems);
        unsigned* hb    = (unsigned*)(ec_sorted + n_edges);

        bool use_bf16 = (need_bf16 <= ws_size);

        hipMemsetAsync(deg, 0, (size_t)n_nodes * 4, stream);
        if (use_bf16) {
            size_t n2 = n_hb;  // float2 count == packed-pair count
            int cblocks = (int)((n2 + 255) / 256);
            h2bf16_kernel<<<cblocks, 256, 0, stream>>>(
                reinterpret_cast<const float2*>(h), hb, n2);
        }

        int eblocks = (n_edges + 255) / 256;
        hist_kernel<<<eblocks, 256, 0, stream>>>(dst, deg, n_edges);
        scan1_kernel<<<NB, 256, 0, stream>>>(deg, offs, bsums, n_nodes);
        scan2_kernel<<<1, 256, 0, stream>>>(bsums, NB);
        scan3_kernel<<<NB, 256, 0, stream>>>(offs, bsums, cursor, n_nodes);
        scatter_kernel<<<eblocks, 256, 0, stream>>>(d, w, gate_b, src, dst, sd, ss,
                                                    cursor, ec_sorted, n_edges);
        int gblocks = (n_nodes + 3) / 4;  // 4 waves/block
        if (use_bf16) {
            gather_bf16_kernel<<<gblocks, 256, 0, stream>>>(hb, offs, deg, ec_sorted,
                                                            z, n_nodes, D);
        } else {
            gather_f32_kernel<<<gblocks, 256, 0, stream>>>(h, offs, deg, ec_sorted,
                                                           z, n_nodes, D);
        }
    } else {
        // Fallback: atomic scatter path.
        hipMemsetAsync(d_out, 0, (size_t)out_size * sizeof(float), stream);
        int blocks = (n_edges + 3) / 4;
        edge_scatter_kernel<<<blocks, 256, 0, stream>>>(h, d, w, gate_b, src, dst,
                                                        sd, ss, z, n_edges, D);
    }
}